// Round 1
// baseline (367.576 us; speedup 1.0000x reference)
//
#include <hip/hip_runtime.h>
#include <stdint.h>

#define NNODES 32768
#define NREL 10
#define NBASES 4
#define DIM 256
#define NEDGE 524288
#define KW 1280                 /* 4*256 basis + 256 root */
#define KBASE 1024              /* z width */

#define HB 2048                 /* hist blocks  */
#define CB 8192                 /* conv blocks  */
#define WB 80                   /* build_wt blocks per layer (20 k x 4 n) */

typedef __attribute__((ext_vector_type(8))) short bf16x8;
typedef __attribute__((ext_vector_type(4))) float f32x4;
typedef __attribute__((ext_vector_type(2))) float f32x2;
typedef __attribute__((ext_vector_type(8))) unsigned short u16x8;

__device__ __forceinline__ float bf2f(unsigned short u){
  union { unsigned int i; float f; } v; v.i = ((unsigned int)u) << 16; return v.f;
}
__device__ __forceinline__ unsigned short f2bf(float f){
  union { float f; unsigned int i; } v; v.f = f;
  unsigned int x = v.i;
  unsigned int r = (x + 0x7FFFu + ((x >> 16) & 1u)) >> 16;
  return (unsigned short)r;
}
__device__ __forceinline__ void gll16(const void* g, void* l){
  __builtin_amdgcn_global_load_lds((const __attribute__((address_space(1))) void*)g,
                                   (__attribute__((address_space(3))) void*)l, 16, 0, 0);
}

// ---- mega: fused independent prep  (hist | conv fp32->bf16 | build Wt0,Wt1)
__global__ __launch_bounds__(256) void mega_prep(
    const int* __restrict__ ec, const int* __restrict__ rel,
    int* __restrict__ cnt_rd,
    const float* __restrict__ x, unsigned short* __restrict__ Xh,
    const float* __restrict__ basis0, const float* __restrict__ root0,
    unsigned short* __restrict__ Wt0,
    const float* __restrict__ basis1, const float* __restrict__ root1,
    unsigned short* __restrict__ Wt1)
{
  __shared__ float tile[64][65];
  int bid = blockIdx.x;
  int t = threadIdx.x;
  if (bid < HB){
    // ---- histogram over (rel, dst)
    int e = bid * 256 + t;
    int d = ec[NEDGE + e];
    int r = rel[e];
    atomicAdd(&cnt_rd[(r << 15) + d], 1);
  } else if (bid < HB + CB){
    // ---- x fp32 -> bf16
    int i = (bid - HB) * 256 + t;
    float4 v = ((const float4*)x)[i];
    ushort4 o; o.x = f2bf(v.x); o.y = f2bf(v.y); o.z = f2bf(v.z); o.w = f2bf(v.w);
    ((ushort4*)Xh)[i] = o;
  } else {
    // ---- build Wt[n][k] = stacked [basis;root]^T via LDS transpose
    int b = bid - HB - CB;
    int layer = b / WB; b %= WB;
    const float* basis = layer ? basis1 : basis0;
    const float* root  = layer ? root1  : root0;
    unsigned short* Wt = layer ? Wt1    : Wt0;
    int k0 = (b % 20) * 64;
    int n0 = (b / 20) * 64;
    int tn = t & 63, tk = t >> 6;
#pragma unroll
    for (int i = 0; i < 64; i += 4){
      int k = k0 + tk + i;
      float v = (k < KBASE) ? basis[(size_t)k * 256 + n0 + tn]
                            : root[(size_t)(k - KBASE) * 256 + n0 + tn];
      tile[tk + i][tn] = v;
    }
    __syncthreads();
#pragma unroll
    for (int i = 0; i < 64; i += 4){
      int n = n0 + tk + i;
      Wt[(size_t)n * KW + k0 + tn] = f2bf(tile[tn][tk + i]);
    }
  }
}

// ---------------- 3-phase exclusive scan over deg (deg = sum_r cnt_rd[r,d])
__global__ __launch_bounds__(1024) void scan1(const int* __restrict__ cnt_rd,
                                              int* __restrict__ offs, int* __restrict__ blksum)
{
  __shared__ int sh[1024];
  int tid = threadIdx.x; int gid = blockIdx.x * 1024 + tid;
  int v = 0;
#pragma unroll
  for (int r = 0; r < NREL; r++) v += cnt_rd[(r << 15) + gid];
  sh[tid] = v; __syncthreads();
  for (int off = 1; off < 1024; off <<= 1){
    int t = (tid >= off) ? sh[tid - off] : 0;
    __syncthreads(); sh[tid] += t; __syncthreads();
  }
  offs[gid] = sh[tid] - v;
  if (tid == 1023) blksum[blockIdx.x] = sh[1023];
}
__global__ __launch_bounds__(64) void scan2(int* __restrict__ blksum)
{
  __shared__ int sh[64];
  int tid = threadIdx.x;
  int v = (tid < NNODES / 1024) ? blksum[tid] : 0;
  sh[tid] = v; __syncthreads();
  for (int off = 1; off < 64; off <<= 1){
    int t = (tid >= off) ? sh[tid - off] : 0;
    __syncthreads(); sh[tid] += t; __syncthreads();
  }
  if (tid < NNODES / 1024) blksum[tid] = sh[tid] - v;
}
__global__ __launch_bounds__(1024) void scan3(int* __restrict__ offs, const int* __restrict__ blksum)
{
  int gid = blockIdx.x * 1024 + threadIdx.x;
  offs[gid] += blksum[blockIdx.x];
  if (gid == 0) offs[NNODES] = NEDGE;
}

// --------------------------- bucket scatter: sort by dst, pack (src<<4 | r)
__global__ void scatter_kernel(const int* __restrict__ ec, const int* __restrict__ rel,
                               const int* __restrict__ offs, int* __restrict__ cursor,
                               unsigned int* __restrict__ meta)
{
  int e = blockIdx.x * 256 + threadIdx.x;
  int s = ec[e];
  int d = ec[NEDGE + e];
  int r = rel[e];
  int p = offs[d] + atomicAdd(&cursor[d], 1);
  meta[p] = ((unsigned int)s << 4) | (unsigned int)r;
}

// --------- fused comp-weighted segment sums; half-wave edge pairing
// lanes 0..31 process even edges, lanes 32..63 odd edges of the same dst;
// each lane covers 8 columns (16B dwordx4 gather); float2 packed accumulate.
__global__ __launch_bounds__(256) void agg6(
    const unsigned short* __restrict__ Xin,   // [N,256] bf16
    const int* __restrict__ offs,             // [N+1]
    const unsigned int* __restrict__ meta,    // packed src<<4|r
    const float* __restrict__ comp,           // [NREL*NBASES] fp32
    const int* __restrict__ cnt_rd,           // [NREL, N]
    unsigned short* __restrict__ z)           // [N, KBASE] bf16
{
  __shared__ __attribute__((aligned(16))) float wtab[4][40];  // [wave][r*4+b]
  int t = threadIdx.x;
  int wv = t >> 6, lane = t & 63;
  int d = blockIdx.x * 4 + wv;
  if (lane < 40){
    int r = lane >> 2, b = lane & 3;
    int cnt = cnt_rd[(r << 15) + d];
    wtab[wv][lane] = (cnt > 0) ? comp[r * NBASES + b] / (float)cnt : 0.0f;
  }
  __syncthreads();

  const float4* wt4 = (const float4*)&wtab[wv][0];   // indexed by r
  int h = lane >> 5;                  // half id (edge parity)
  unsigned cl8 = (unsigned)((lane & 31) * 8);  // first column this lane owns

  f32x2 acc[4][4];                    // [base][col-pair]
#pragma unroll
  for (int b = 0; b < 4; b++)
#pragma unroll
    for (int j = 0; j < 4; j++) acc[b][j] = (f32x2){0.f, 0.f};

  int e0 = offs[d], e1 = offs[d + 1];
  int e = e0;
  // main loop: both halves have a valid edge
#pragma unroll 2
  for (; e + 1 < e1; e += 2){
    unsigned int m = meta[e + h];
    float4 w4 = wt4[m & 15u];
    f32x2 wd0 = {w4.x, w4.x}, wd1 = {w4.y, w4.y};
    f32x2 wd2 = {w4.z, w4.z}, wd3 = {w4.w, w4.w};
    union { uint4 q; unsigned int u[4]; } V;
    V.q = *(const uint4*)(Xin + (unsigned)(m >> 4) * 256u + cl8);
#pragma unroll
    for (int j = 0; j < 4; j++){
      unsigned int u = V.u[j];
      union { unsigned int i; float f; } lo, hi;
      lo.i = u << 16; hi.i = u & 0xffff0000u;
      f32x2 vv = {lo.f, hi.f};
      acc[0][j] += wd0 * vv;
      acc[1][j] += wd1 * vv;
      acc[2][j] += wd2 * vv;
      acc[3][j] += wd3 * vv;
    }
  }
  // tail: one leftover edge, only half 0 active
  if (e < e1){
    bool act = (h == 0);
    unsigned int m = meta[act ? e : e0];
    float4 w4 = wt4[m & 15u];
    if (!act){ w4.x = 0.f; w4.y = 0.f; w4.z = 0.f; w4.w = 0.f; }
    f32x2 wd0 = {w4.x, w4.x}, wd1 = {w4.y, w4.y};
    f32x2 wd2 = {w4.z, w4.z}, wd3 = {w4.w, w4.w};
    union { uint4 q; unsigned int u[4]; } V;
    V.q = *(const uint4*)(Xin + (unsigned)(m >> 4) * 256u + cl8);
#pragma unroll
    for (int j = 0; j < 4; j++){
      unsigned int u = V.u[j];
      union { unsigned int i; float f; } lo, hi;
      lo.i = u << 16; hi.i = u & 0xffff0000u;
      f32x2 vv = {lo.f, hi.f};
      acc[0][j] += wd0 * vv;
      acc[1][j] += wd1 * vv;
      acc[2][j] += wd2 * vv;
      acc[3][j] += wd3 * vv;
    }
  }

  // cross-half reduction: both halves end with the full edge sum
#pragma unroll
  for (int b = 0; b < 4; b++)
#pragma unroll
    for (int j = 0; j < 4; j++){
      acc[b][j].x += __shfl_xor(acc[b][j].x, 32);
      acc[b][j].y += __shfl_xor(acc[b][j].y, 32);
    }

  // store: half 0 writes bases 0,1 ; half 1 writes bases 2,3 (16B each)
  u16x8 o0, o1;
#pragma unroll
  for (int j = 0; j < 4; j++){
    f32x2 p = (h == 0) ? acc[0][j] : acc[2][j];
    f32x2 q = (h == 0) ? acc[1][j] : acc[3][j];
    o0[2 * j]     = f2bf(p.x);
    o0[2 * j + 1] = f2bf(p.y);
    o1[2 * j]     = f2bf(q.x);
    o1[2 * j + 1] = f2bf(q.y);
  }
  size_t zb = (size_t)d * KBASE + cl8;
  unsigned bofs = (unsigned)(h * 512);
  *(u16x8*)(z + zb + bofs) = o0;
  *(u16x8*)(z + zb + bofs + 256) = o1;
}

// ---- MFMA GEMM: Y[M,256] = [z | ext] @ Wt^T + bias  (tile 64m x 256n, K=1280)
// mode 1: outh = relu(v) bf16 ; mode 2: outf = v fp32
// LDS k-slot XOR swizzle: granule (row, kc) lives at slot (kc + (row>>1))&3
__global__ __launch_bounds__(256) void gemm4(
    const unsigned short* __restrict__ A0,   // z [M,KBASE]
    const unsigned short* __restrict__ A1,   // ext [M,256]
    const unsigned short* __restrict__ Wt,   // [256,KW]
    const float* __restrict__ bias,
    unsigned short* __restrict__ outh,
    float* __restrict__ outf,
    int mode)
{
  __shared__ __attribute__((aligned(16))) short As[64 * 32];    // 4 KB
  __shared__ __attribute__((aligned(16))) short Bs[256 * 32];   // 16 KB
  int tid  = threadIdx.x;
  int m0   = blockIdx.x * 64;
  int lane = tid & 63;
  int wn   = tid >> 6;               // wave = n-slice 0..3
  int lq = lane >> 4, lr = lane & 15;

  f32x4 zero = {0.f, 0.f, 0.f, 0.f};
  f32x4 acc[4][4];
#pragma unroll
  for (int i = 0; i < 4; i++)
#pragma unroll
    for (int j = 0; j < 4; j++) acc[i][j] = zero;

  // A staging source params (row = tid>>2, kc = inverse swizzle)
  int arow = tid >> 2;
  int akc  = ((tid & 3) - (tid >> 3)) & 3;

  for (int k0 = 0; k0 < KW; k0 += 32){
    __syncthreads();
    {
      const unsigned short* ga;
      if (k0 < KBASE) ga = A0 + (size_t)(m0 + arow) * KBASE + k0 + akc * 8;
      else            ga = A1 + (size_t)(m0 + arow) * 256 + (k0 - KBASE) + akc * 8;
      gll16(ga, As + tid * 8);
    }
#pragma unroll
    for (int i = 0; i < 4; i++){
      int gb  = tid + i * 256;             // 0..1023 B granules
      int row = gb >> 2;
      int kc  = ((gb & 3) - (gb >> 3)) & 3;
      gll16(Wt + (size_t)row * KW + k0 + kc * 8, Bs + gb * 8);
    }
    __syncthreads();

    bf16x8 af[4], bfr[4];
#pragma unroll
    for (int i = 0; i < 4; i++){
      int row = i * 16 + lr;
      af[i] = *(const bf16x8*)(As + row * 32 + (((lq + (row >> 1)) & 3) * 8));
    }
#pragma unroll
    for (int j = 0; j < 4; j++){
      int row = wn * 64 + j * 16 + lr;
      bfr[j] = *(const bf16x8*)(Bs + row * 32 + (((lq + (row >> 1)) & 3) * 8));
    }
#pragma unroll
    for (int i = 0; i < 4; i++)
#pragma unroll
      for (int j = 0; j < 4; j++)
        acc[i][j] = __builtin_amdgcn_mfma_f32_16x16x32_bf16(af[i], bfr[j], acc[i][j], 0, 0, 0);
  }

  // C/D mapping: col=lane&15, row=(lane>>4)*4+reg  [m89/m91]
#pragma unroll
  for (int i = 0; i < 4; i++)
#pragma unroll
    for (int j = 0; j < 4; j++)
#pragma unroll
      for (int r = 0; r < 4; r++){
        int gm = m0 + i * 16 + lq * 4 + r;
        int gn = wn * 64 + j * 16 + lr;
        float v = acc[i][j][r] + bias[gn];
        size_t idx = (size_t)gm * 256 + gn;
        if (mode == 1) outh[idx] = f2bf(fmaxf(v, 0.f));
        else           outf[idx] = v;
      }
}

// ---------------------------------------------------------------------------
extern "C" void kernel_launch(void* const* d_in, const int* in_sizes, int n_in,
                              void* d_out, int out_size, void* d_ws, size_t ws_size,
                              hipStream_t stream)
{
  const float* x      = (const float*)d_in[0];
  const int*   ec     = (const int*)d_in[3];
  const int*   rel    = (const int*)d_in[4];
  const float* basis0 = (const float*)d_in[5];
  const float* comp0  = (const float*)d_in[6];
  const float* root0  = (const float*)d_in[7];
  const float* bias0  = (const float*)d_in[8];
  const float* basis1 = (const float*)d_in[9];
  const float* comp1  = (const float*)d_in[10];
  const float* root1  = (const float*)d_in[11];
  const float* bias1  = (const float*)d_in[12];

  char* p = (char*)d_ws;
  unsigned short* z   = (unsigned short*)p; p += (size_t)NNODES * KBASE * 2;  // 67.1 MB
  unsigned short* Xh  = (unsigned short*)p; p += (size_t)NNODES * DIM * 2;    // 16.8
  unsigned short* h   = (unsigned short*)p; p += (size_t)NNODES * DIM * 2;    // 16.8
  unsigned short* Wt0 = (unsigned short*)p; p += (size_t)256 * KW * 2;        // 0.66
  unsigned short* Wt1 = (unsigned short*)p; p += (size_t)256 * KW * 2;        // 0.66
  unsigned int* meta  = (unsigned int*)p;   p += (size_t)NEDGE * 4;           // 2.1
  int* cnt_rd  = (int*)p;   p += (size_t)NREL * NNODES * 4;                   // 1.3
  int* cursor  = (int*)p;   p += (size_t)NNODES * 4;
  int* offs    = (int*)p;   p += (size_t)(NNODES + 1) * 4;
  int* blksum  = (int*)p;   p += 1024;

  // zero cnt_rd + cursor (contiguous)
  hipMemsetAsync(cnt_rd, 0, ((size_t)NREL * NNODES + (size_t)NNODES) * 4, stream);

  // ---- fused prep: hist | conv | build Wt0 | build Wt1 ----
  mega_prep<<<HB + CB + 2 * WB, 256, 0, stream>>>(
      ec, rel, cnt_rd, x, Xh, basis0, root0, Wt0, basis1, root1, Wt1);

  scan1<<<NNODES / 1024, 1024, 0, stream>>>(cnt_rd, offs, blksum);
  scan2<<<1, 64, 0, stream>>>(blksum);
  scan3<<<NNODES / 1024, 1024, 0, stream>>>(offs, blksum);
  scatter_kernel<<<NEDGE / 256, 256, 0, stream>>>(ec, rel, offs, cursor, meta);

  // ---- layer 0 ----
  agg6<<<NNODES / 4, 256, 0, stream>>>(Xh, offs, meta, comp0, cnt_rd, z);
  gemm4<<<NNODES / 64, 256, 0, stream>>>(z, Xh, Wt0, bias0, h, nullptr, 1);

  // ---- layer 1 ----
  agg6<<<NNODES / 4, 256, 0, stream>>>(h, offs, meta, comp1, cnt_rd, z);
  gemm4<<<NNODES / 64, 256, 0, stream>>>(z, h, Wt1, bias1, nullptr, (float*)d_out, 2);
}

// Round 2
// 331.216 us; speedup vs baseline: 1.1098x; 1.1098x over previous
//
#include <hip/hip_runtime.h>
#include <stdint.h>

#define NNODES 32768
#define NREL 10
#define NBASES 4
#define DIM 256
#define NEDGE 524288
#define KW 1280                 /* 4*256 basis + 256 root */
#define KBASE 1024              /* z width */

#define HB 2048                 /* hist blocks  */
#define CB 8192                 /* conv blocks  */
#define WB 80                   /* build_wt blocks per layer (20 k x 4 n) */

typedef __attribute__((ext_vector_type(8))) short bf16x8;
typedef __attribute__((ext_vector_type(4))) float f32x4;

__device__ __forceinline__ float bf2f(unsigned short u){
  union { unsigned int i; float f; } v; v.i = ((unsigned int)u) << 16; return v.f;
}
__device__ __forceinline__ unsigned short f2bf(float f){
  union { float f; unsigned int i; } v; v.f = f;
  unsigned int x = v.i;
  unsigned int r = (x + 0x7FFFu + ((x >> 16) & 1u)) >> 16;
  return (unsigned short)r;
}
__device__ __forceinline__ void gll16(const void* g, void* l){
  __builtin_amdgcn_global_load_lds((const __attribute__((address_space(1))) void*)g,
                                   (__attribute__((address_space(3))) void*)l, 16, 0, 0);
}

// ---- mega: fused independent prep  (hist | conv fp32->bf16 | build Wt0,Wt1)
__global__ __launch_bounds__(256) void mega_prep(
    const int* __restrict__ ec, const int* __restrict__ rel,
    int* __restrict__ cnt_rd,
    const float* __restrict__ x, unsigned short* __restrict__ Xh,
    const float* __restrict__ basis0, const float* __restrict__ root0,
    unsigned short* __restrict__ Wt0,
    const float* __restrict__ basis1, const float* __restrict__ root1,
    unsigned short* __restrict__ Wt1)
{
  __shared__ float tile[64][65];
  int bid = blockIdx.x;
  int t = threadIdx.x;
  if (bid < HB){
    // ---- histogram over (rel, dst)
    int e = bid * 256 + t;
    int d = ec[NEDGE + e];
    int r = rel[e];
    atomicAdd(&cnt_rd[(r << 15) + d], 1);
  } else if (bid < HB + CB){
    // ---- x fp32 -> bf16
    int i = (bid - HB) * 256 + t;
    float4 v = ((const float4*)x)[i];
    ushort4 o; o.x = f2bf(v.x); o.y = f2bf(v.y); o.z = f2bf(v.z); o.w = f2bf(v.w);
    ((ushort4*)Xh)[i] = o;
  } else {
    // ---- build Wt[n][k] = stacked [basis;root]^T via LDS transpose
    int b = bid - HB - CB;
    int layer = b / WB; b %= WB;
    const float* basis = layer ? basis1 : basis0;
    const float* root  = layer ? root1  : root0;
    unsigned short* Wt = layer ? Wt1    : Wt0;
    int k0 = (b % 20) * 64;
    int n0 = (b / 20) * 64;
    int tn = t & 63, tk = t >> 6;
#pragma unroll
    for (int i = 0; i < 64; i += 4){
      int k = k0 + tk + i;
      float v = (k < KBASE) ? basis[(size_t)k * 256 + n0 + tn]
                            : root[(size_t)(k - KBASE) * 256 + n0 + tn];
      tile[tk + i][tn] = v;
    }
    __syncthreads();
#pragma unroll
    for (int i = 0; i < 64; i += 4){
      int n = n0 + tk + i;
      Wt[(size_t)n * KW + k0 + tn] = f2bf(tile[tn][tk + i]);
    }
  }
}

// ---------------- 3-phase exclusive scan over deg (deg = sum_r cnt_rd[r,d])
__global__ __launch_bounds__(1024) void scan1(const int* __restrict__ cnt_rd,
                                              int* __restrict__ offs, int* __restrict__ blksum)
{
  __shared__ int sh[1024];
  int tid = threadIdx.x; int gid = blockIdx.x * 1024 + tid;
  int v = 0;
#pragma unroll
  for (int r = 0; r < NREL; r++) v += cnt_rd[(r << 15) + gid];
  sh[tid] = v; __syncthreads();
  for (int off = 1; off < 1024; off <<= 1){
    int t = (tid >= off) ? sh[tid - off] : 0;
    __syncthreads(); sh[tid] += t; __syncthreads();
  }
  offs[gid] = sh[tid] - v;
  if (tid == 1023) blksum[blockIdx.x] = sh[1023];
}
__global__ __launch_bounds__(64) void scan2(int* __restrict__ blksum)
{
  __shared__ int sh[64];
  int tid = threadIdx.x;
  int v = (tid < NNODES / 1024) ? blksum[tid] : 0;
  sh[tid] = v; __syncthreads();
  for (int off = 1; off < 64; off <<= 1){
    int t = (tid >= off) ? sh[tid - off] : 0;
    __syncthreads(); sh[tid] += t; __syncthreads();
  }
  if (tid < NNODES / 1024) blksum[tid] = sh[tid] - v;
}
__global__ __launch_bounds__(1024) void scan3(int* __restrict__ offs, const int* __restrict__ blksum)
{
  int gid = blockIdx.x * 1024 + threadIdx.x;
  offs[gid] += blksum[blockIdx.x];
  if (gid == 0) offs[NNODES] = NEDGE;
}

// --------------------------- bucket scatter: sort by dst, pack (src<<4 | r)
__global__ void scatter_kernel(const int* __restrict__ ec, const int* __restrict__ rel,
                               const int* __restrict__ offs, int* __restrict__ cursor,
                               unsigned int* __restrict__ meta)
{
  int e = blockIdx.x * 256 + threadIdx.x;
  int s = ec[e];
  int d = ec[NEDGE + e];
  int r = rel[e];
  int p = offs[d] + atomicAdd(&cursor[d], 1);
  meta[p] = ((unsigned int)s << 4) | (unsigned int)r;
}

// --------- fused comp-weighted segment sums; per-dst LDS weight table
// agg7 = agg5 structure (full-wave row, hoisted gather batch) with:
//  * 8-edge unroll: 8 independent global gather chains in flight per wave
//  * predicated 4-edge tail group (w=0 for invalid) -> no scalar tail loop
__global__ __launch_bounds__(256) void agg7(
    const unsigned short* __restrict__ Xin,   // [N,256] bf16
    const int* __restrict__ offs,             // [N+1]
    const unsigned int* __restrict__ meta,    // packed src<<4|r
    const float* __restrict__ comp,           // [NREL*NBASES] fp32
    const int* __restrict__ cnt_rd,           // [NREL, N]
    unsigned short* __restrict__ z)           // [N, KBASE] bf16
{
  __shared__ __attribute__((aligned(16))) float wtab[4][40];  // [wave][r*4+b]
  int t = threadIdx.x;
  int wv = t >> 6, lane = t & 63;
  int d = blockIdx.x * 4 + wv;
  if (lane < 40){
    int r = lane >> 2, b = lane & 3;
    int cnt = cnt_rd[(r << 15) + d];
    wtab[wv][lane] = (cnt > 0) ? comp[r * NBASES + b] / (float)cnt : 0.0f;
  }
  __syncthreads();

  int col = lane * 4;
  const float4* wt4 = (const float4*)&wtab[wv][0];   // indexed by r

  float acc[NBASES][4] = {};
  int e0 = offs[d], e1 = offs[d + 1];
  int e = e0;

  // ---- main: 8 edges per iteration, all gathers issued before consumption
  for (; e + 7 < e1; e += 8){
    unsigned int m[8];
#pragma unroll
    for (int i = 0; i < 8; i++) m[i] = meta[e + i];
    ushort4 v[8];
#pragma unroll
    for (int i = 0; i < 8; i++)
      v[i] = *(const ushort4*)(Xin + ((size_t)(m[i] >> 4)) * 256 + col);
#pragma unroll
    for (int i = 0; i < 8; i++){
      float4 w = wt4[m[i] & 15u];
      float f0 = bf2f(v[i].x), f1 = bf2f(v[i].y), f2 = bf2f(v[i].z), f3 = bf2f(v[i].w);
      acc[0][0] += w.x * f0; acc[0][1] += w.x * f1; acc[0][2] += w.x * f2; acc[0][3] += w.x * f3;
      acc[1][0] += w.y * f0; acc[1][1] += w.y * f1; acc[1][2] += w.y * f2; acc[1][3] += w.y * f3;
      acc[2][0] += w.z * f0; acc[2][1] += w.z * f1; acc[2][2] += w.z * f2; acc[2][3] += w.z * f3;
      acc[3][0] += w.w * f0; acc[3][1] += w.w * f1; acc[3][2] += w.w * f2; acc[3][3] += w.w * f3;
    }
  }

  // ---- tail: predicated 4-edge groups (invalid edges: w=0, index clamped)
  for (; e < e1; e += 4){
    unsigned int m[4];
    float4 w[4];
#pragma unroll
    for (int i = 0; i < 4; i++){
      int ei = e + i;
      bool ok = ei < e1;
      m[i] = meta[ok ? ei : e1 - 1];
      float4 ww = wt4[m[i] & 15u];
      if (!ok){ ww.x = 0.f; ww.y = 0.f; ww.z = 0.f; ww.w = 0.f; }
      w[i] = ww;
    }
    ushort4 v[4];
#pragma unroll
    for (int i = 0; i < 4; i++)
      v[i] = *(const ushort4*)(Xin + ((size_t)(m[i] >> 4)) * 256 + col);
#pragma unroll
    for (int i = 0; i < 4; i++){
      float f0 = bf2f(v[i].x), f1 = bf2f(v[i].y), f2 = bf2f(v[i].z), f3 = bf2f(v[i].w);
      acc[0][0] += w[i].x * f0; acc[0][1] += w[i].x * f1; acc[0][2] += w[i].x * f2; acc[0][3] += w[i].x * f3;
      acc[1][0] += w[i].y * f0; acc[1][1] += w[i].y * f1; acc[1][2] += w[i].y * f2; acc[1][3] += w[i].y * f3;
      acc[2][0] += w[i].z * f0; acc[2][1] += w[i].z * f1; acc[2][2] += w[i].z * f2; acc[2][3] += w[i].z * f3;
      acc[3][0] += w[i].w * f0; acc[3][1] += w[i].w * f1; acc[3][2] += w[i].w * f2; acc[3][3] += w[i].w * f3;
    }
  }

#pragma unroll
  for (int b = 0; b < NBASES; b++){
    ushort4 o;
    o.x = f2bf(acc[b][0]); o.y = f2bf(acc[b][1]);
    o.z = f2bf(acc[b][2]); o.w = f2bf(acc[b][3]);
    *(ushort4*)(z + (size_t)d * KBASE + b * 256 + col) = o;
  }
}

// ---- MFMA GEMM: Y[M,256] = [z | ext] @ Wt^T + bias  (tile 64m x 256n, K=1280)
// mode 1: outh = relu(v) bf16 ; mode 2: outf = v fp32
// LDS k-slot XOR swizzle: granule (row, kc) lives at slot (kc + (row>>1))&3
__global__ __launch_bounds__(256) void gemm4(
    const unsigned short* __restrict__ A0,   // z [M,KBASE]
    const unsigned short* __restrict__ A1,   // ext [M,256]
    const unsigned short* __restrict__ Wt,   // [256,KW]
    const float* __restrict__ bias,
    unsigned short* __restrict__ outh,
    float* __restrict__ outf,
    int mode)
{
  __shared__ __attribute__((aligned(16))) short As[64 * 32];    // 4 KB
  __shared__ __attribute__((aligned(16))) short Bs[256 * 32];   // 16 KB
  int tid  = threadIdx.x;
  int m0   = blockIdx.x * 64;
  int lane = tid & 63;
  int wn   = tid >> 6;               // wave = n-slice 0..3
  int lq = lane >> 4, lr = lane & 15;

  f32x4 zero = {0.f, 0.f, 0.f, 0.f};
  f32x4 acc[4][4];
#pragma unroll
  for (int i = 0; i < 4; i++)
#pragma unroll
    for (int j = 0; j < 4; j++) acc[i][j] = zero;

  // A staging source params (row = tid>>2, kc = inverse swizzle)
  int arow = tid >> 2;
  int akc  = ((tid & 3) - (tid >> 3)) & 3;

  for (int k0 = 0; k0 < KW; k0 += 32){
    __syncthreads();
    {
      const unsigned short* ga;
      if (k0 < KBASE) ga = A0 + (size_t)(m0 + arow) * KBASE + k0 + akc * 8;
      else            ga = A1 + (size_t)(m0 + arow) * 256 + (k0 - KBASE) + akc * 8;
      gll16(ga, As + tid * 8);
    }
#pragma unroll
    for (int i = 0; i < 4; i++){
      int gb  = tid + i * 256;             // 0..1023 B granules
      int row = gb >> 2;
      int kc  = ((gb & 3) - (gb >> 3)) & 3;
      gll16(Wt + (size_t)row * KW + k0 + kc * 8, Bs + gb * 8);
    }
    __syncthreads();

    bf16x8 af[4], bfr[4];
#pragma unroll
    for (int i = 0; i < 4; i++){
      int row = i * 16 + lr;
      af[i] = *(const bf16x8*)(As + row * 32 + (((lq + (row >> 1)) & 3) * 8));
    }
#pragma unroll
    for (int j = 0; j < 4; j++){
      int row = wn * 64 + j * 16 + lr;
      bfr[j] = *(const bf16x8*)(Bs + row * 32 + (((lq + (row >> 1)) & 3) * 8));
    }
#pragma unroll
    for (int i = 0; i < 4; i++)
#pragma unroll
      for (int j = 0; j < 4; j++)
        acc[i][j] = __builtin_amdgcn_mfma_f32_16x16x32_bf16(af[i], bfr[j], acc[i][j], 0, 0, 0);
  }

  // C/D mapping: col=lane&15, row=(lane>>4)*4+reg  [m89/m91]
#pragma unroll
  for (int i = 0; i < 4; i++)
#pragma unroll
    for (int j = 0; j < 4; j++)
#pragma unroll
      for (int r = 0; r < 4; r++){
        int gm = m0 + i * 16 + lq * 4 + r;
        int gn = wn * 64 + j * 16 + lr;
        float v = acc[i][j][r] + bias[gn];
        size_t idx = (size_t)gm * 256 + gn;
        if (mode == 1) outh[idx] = f2bf(fmaxf(v, 0.f));
        else           outf[idx] = v;
      }
}

// ---------------------------------------------------------------------------
extern "C" void kernel_launch(void* const* d_in, const int* in_sizes, int n_in,
                              void* d_out, int out_size, void* d_ws, size_t ws_size,
                              hipStream_t stream)
{
  const float* x      = (const float*)d_in[0];
  const int*   ec     = (const int*)d_in[3];
  const int*   rel    = (const int*)d_in[4];
  const float* basis0 = (const float*)d_in[5];
  const float* comp0  = (const float*)d_in[6];
  const float* root0  = (const float*)d_in[7];
  const float* bias0  = (const float*)d_in[8];
  const float* basis1 = (const float*)d_in[9];
  const float* comp1  = (const float*)d_in[10];
  const float* root1  = (const float*)d_in[11];
  const float* bias1  = (const float*)d_in[12];

  char* p = (char*)d_ws;
  unsigned short* z   = (unsigned short*)p; p += (size_t)NNODES * KBASE * 2;  // 67.1 MB
  unsigned short* Xh  = (unsigned short*)p; p += (size_t)NNODES * DIM * 2;    // 16.8
  unsigned short* h   = (unsigned short*)p; p += (size_t)NNODES * DIM * 2;    // 16.8
  unsigned short* Wt0 = (unsigned short*)p; p += (size_t)256 * KW * 2;        // 0.66
  unsigned short* Wt1 = (unsigned short*)p; p += (size_t)256 * KW * 2;        // 0.66
  unsigned int* meta  = (unsigned int*)p;   p += (size_t)NEDGE * 4;           // 2.1
  int* cnt_rd  = (int*)p;   p += (size_t)NREL * NNODES * 4;                   // 1.3
  int* cursor  = (int*)p;   p += (size_t)NNODES * 4;
  int* offs    = (int*)p;   p += (size_t)(NNODES + 1) * 4;
  int* blksum  = (int*)p;   p += 1024;

  // zero cnt_rd + cursor (contiguous)
  hipMemsetAsync(cnt_rd, 0, ((size_t)NREL * NNODES + (size_t)NNODES) * 4, stream);

  // ---- fused prep: hist | conv | build Wt0 | build Wt1 ----
  mega_prep<<<HB + CB + 2 * WB, 256, 0, stream>>>(
      ec, rel, cnt_rd, x, Xh, basis0, root0, Wt0, basis1, root1, Wt1);

  scan1<<<NNODES / 1024, 1024, 0, stream>>>(cnt_rd, offs, blksum);
  scan2<<<1, 64, 0, stream>>>(blksum);
  scan3<<<NNODES / 1024, 1024, 0, stream>>>(offs, blksum);
  scatter_kernel<<<NEDGE / 256, 256, 0, stream>>>(ec, rel, offs, cursor, meta);

  // ---- layer 0 ----
  agg7<<<NNODES / 4, 256, 0, stream>>>(Xh, offs, meta, comp0, cnt_rd, z);
  gemm4<<<NNODES / 64, 256, 0, stream>>>(z, Xh, Wt0, bias0, h, nullptr, 1);

  // ---- layer 1 ----
  agg7<<<NNODES / 4, 256, 0, stream>>>(h, offs, meta, comp1, cnt_rd, z);
  gemm4<<<NNODES / 64, 256, 0, stream>>>(z, h, Wt1, bias1, nullptr, (float*)d_out, 2);
}

// Round 3
// 322.768 us; speedup vs baseline: 1.1388x; 1.0262x over previous
//
#include <hip/hip_runtime.h>
#include <stdint.h>

#define NNODES 32768
#define NREL 10
#define NBASES 4
#define DIM 256
#define NEDGE 524288
#define KW 1280                 /* 4*256 basis + 256 root */
#define KBASE 1024              /* z width */

#define HB 2048                 /* hist blocks  */
#define CB 8192                 /* conv blocks  */
#define WB 80                   /* build_wt blocks per layer (20 k x 4 n) */

typedef __attribute__((ext_vector_type(8))) short bf16x8;
typedef __attribute__((ext_vector_type(4))) float f32x4;
typedef __attribute__((ext_vector_type(2))) float f32x2;

__device__ __forceinline__ float bf2f(unsigned short u){
  union { unsigned int i; float f; } v; v.i = ((unsigned int)u) << 16; return v.f;
}
__device__ __forceinline__ float asf(unsigned int u){
  union { unsigned int i; float f; } v; v.i = u; return v.f;
}
__device__ __forceinline__ unsigned short f2bf(float f){
  union { float f; unsigned int i; } v; v.f = f;
  unsigned int x = v.i;
  unsigned int r = (x + 0x7FFFu + ((x >> 16) & 1u)) >> 16;
  return (unsigned short)r;
}
__device__ __forceinline__ void gll16(const void* g, void* l){
  __builtin_amdgcn_global_load_lds((const __attribute__((address_space(1))) void*)g,
                                   (__attribute__((address_space(3))) void*)l, 16, 0, 0);
}

// ---- mega: fused independent prep  (hist | conv fp32->bf16 | build Wt0,Wt1)
__global__ __launch_bounds__(256) void mega_prep(
    const int* __restrict__ ec, const int* __restrict__ rel,
    int* __restrict__ cnt_rd,
    const float* __restrict__ x, unsigned short* __restrict__ Xh,
    const float* __restrict__ basis0, const float* __restrict__ root0,
    unsigned short* __restrict__ Wt0,
    const float* __restrict__ basis1, const float* __restrict__ root1,
    unsigned short* __restrict__ Wt1)
{
  __shared__ float tile[64][65];
  int bid = blockIdx.x;
  int t = threadIdx.x;
  if (bid < HB){
    // ---- histogram over (rel, dst)
    int e = bid * 256 + t;
    int d = ec[NEDGE + e];
    int r = rel[e];
    atomicAdd(&cnt_rd[(r << 15) + d], 1);
  } else if (bid < HB + CB){
    // ---- x fp32 -> bf16
    int i = (bid - HB) * 256 + t;
    float4 v = ((const float4*)x)[i];
    ushort4 o; o.x = f2bf(v.x); o.y = f2bf(v.y); o.z = f2bf(v.z); o.w = f2bf(v.w);
    ((ushort4*)Xh)[i] = o;
  } else {
    // ---- build Wt[n][k] = stacked [basis;root]^T via LDS transpose
    int b = bid - HB - CB;
    int layer = b / WB; b %= WB;
    const float* basis = layer ? basis1 : basis0;
    const float* root  = layer ? root1  : root0;
    unsigned short* Wt = layer ? Wt1    : Wt0;
    int k0 = (b % 20) * 64;
    int n0 = (b / 20) * 64;
    int tn = t & 63, tk = t >> 6;
#pragma unroll
    for (int i = 0; i < 64; i += 4){
      int k = k0 + tk + i;
      float v = (k < KBASE) ? basis[(size_t)k * 256 + n0 + tn]
                            : root[(size_t)(k - KBASE) * 256 + n0 + tn];
      tile[tk + i][tn] = v;
    }
    __syncthreads();
#pragma unroll
    for (int i = 0; i < 64; i += 4){
      int n = n0 + tk + i;
      Wt[(size_t)n * KW + k0 + tn] = f2bf(tile[tn][tk + i]);
    }
  }
}

// ---------------- 3-phase exclusive scan over deg (deg = sum_r cnt_rd[r,d])
__global__ __launch_bounds__(1024) void scan1(const int* __restrict__ cnt_rd,
                                              int* __restrict__ offs, int* __restrict__ blksum)
{
  __shared__ int sh[1024];
  int tid = threadIdx.x; int gid = blockIdx.x * 1024 + tid;
  int v = 0;
#pragma unroll
  for (int r = 0; r < NREL; r++) v += cnt_rd[(r << 15) + gid];
  sh[tid] = v; __syncthreads();
  for (int off = 1; off < 1024; off <<= 1){
    int t = (tid >= off) ? sh[tid - off] : 0;
    __syncthreads(); sh[tid] += t; __syncthreads();
  }
  offs[gid] = sh[tid] - v;
  if (tid == 1023) blksum[blockIdx.x] = sh[1023];
}
__global__ __launch_bounds__(64) void scan2(int* __restrict__ blksum)
{
  __shared__ int sh[64];
  int tid = threadIdx.x;
  int v = (tid < NNODES / 1024) ? blksum[tid] : 0;
  sh[tid] = v; __syncthreads();
  for (int off = 1; off < 64; off <<= 1){
    int t = (tid >= off) ? sh[tid - off] : 0;
    __syncthreads(); sh[tid] += t; __syncthreads();
  }
  if (tid < NNODES / 1024) blksum[tid] = sh[tid] - v;
}
__global__ __launch_bounds__(1024) void scan3(int* __restrict__ offs, const int* __restrict__ blksum)
{
  int gid = blockIdx.x * 1024 + threadIdx.x;
  offs[gid] += blksum[blockIdx.x];
  if (gid == 0) offs[NNODES] = NEDGE;
}

// --------------------------- bucket scatter: sort by dst, pack (src<<4 | r)
__global__ void scatter_kernel(const int* __restrict__ ec, const int* __restrict__ rel,
                               const int* __restrict__ offs, int* __restrict__ cursor,
                               unsigned int* __restrict__ meta)
{
  int e = blockIdx.x * 256 + threadIdx.x;
  int s = ec[e];
  int d = ec[NEDGE + e];
  int r = rel[e];
  int p = offs[d] + atomicAdd(&cursor[d], 1);
  meta[p] = ((unsigned int)s << 4) | (unsigned int)r;
}

// --------- fused comp-weighted segment sums; per-dst LDS weight table
// agg8 = agg7 memory structure (8 hoisted gather chains, predicated 4-edge
// tail) + packed f32x2 arithmetic (v_pk_fma_f32, full-rate per agg6 evidence)
// + 32-bit gather offsets (saddr-form loads, fewer addr VALU ops).
__global__ __launch_bounds__(256) void agg8(
    const unsigned short* __restrict__ Xin,   // [N,256] bf16
    const int* __restrict__ offs,             // [N+1]
    const unsigned int* __restrict__ meta,    // packed src<<4|r
    const float* __restrict__ comp,           // [NREL*NBASES] fp32
    const int* __restrict__ cnt_rd,           // [NREL, N]
    unsigned short* __restrict__ z)           // [N, KBASE] bf16
{
  __shared__ __attribute__((aligned(16))) float wtab[4][40];  // [wave][r*4+b]
  int t = threadIdx.x;
  int wv = t >> 6, lane = t & 63;
  int d = blockIdx.x * 4 + wv;
  if (lane < 40){
    int r = lane >> 2, b = lane & 3;
    int cnt = cnt_rd[(r << 15) + d];
    wtab[wv][lane] = (cnt > 0) ? comp[r * NBASES + b] / (float)cnt : 0.0f;
  }
  __syncthreads();

  const float4* wt4 = (const float4*)&wtab[wv][0];   // indexed by r
  const char* Xb = (const char*)Xin;
  unsigned colb = (unsigned)(lane * 8);              // byte offset of this lane's 4 cols

  // acc[b][0] = (col0,col1), acc[b][1] = (col2,col3)
  f32x2 acc[NBASES][2];
#pragma unroll
  for (int b = 0; b < NBASES; b++){ acc[b][0] = (f32x2){0.f,0.f}; acc[b][1] = (f32x2){0.f,0.f}; }

  int e0 = offs[d], e1 = offs[d + 1];
  int e = e0;

  // ---- main: 8 edges per iteration, all gathers issued before consumption
  for (; e + 7 < e1; e += 8){
    unsigned int m[8];
#pragma unroll
    for (int i = 0; i < 8; i++) m[i] = meta[e + i];
    uint2 v[8];
#pragma unroll
    for (int i = 0; i < 8; i++){
      unsigned off = ((m[i] & 0xFFFFFFF0u) << 5) + colb;   // (src*512) + lane*8
      v[i] = *(const uint2*)(Xb + off);
    }
#pragma unroll
    for (int i = 0; i < 8; i++){
      float4 w = wt4[m[i] & 15u];
      f32x2 f01, f23;
      f01.x = asf(v[i].x << 16); f01.y = asf(v[i].x & 0xffff0000u);
      f23.x = asf(v[i].y << 16); f23.y = asf(v[i].y & 0xffff0000u);
      acc[0][0] += (f32x2){w.x, w.x} * f01;  acc[0][1] += (f32x2){w.x, w.x} * f23;
      acc[1][0] += (f32x2){w.y, w.y} * f01;  acc[1][1] += (f32x2){w.y, w.y} * f23;
      acc[2][0] += (f32x2){w.z, w.z} * f01;  acc[2][1] += (f32x2){w.z, w.z} * f23;
      acc[3][0] += (f32x2){w.w, w.w} * f01;  acc[3][1] += (f32x2){w.w, w.w} * f23;
    }
  }

  // ---- tail: predicated 4-edge groups (invalid edges: w=0, index clamped)
  for (; e < e1; e += 4){
    unsigned int m[4];
    float4 w[4];
#pragma unroll
    for (int i = 0; i < 4; i++){
      int ei = e + i;
      bool ok = ei < e1;
      m[i] = meta[ok ? ei : e1 - 1];
      float4 ww = wt4[m[i] & 15u];
      if (!ok){ ww.x = 0.f; ww.y = 0.f; ww.z = 0.f; ww.w = 0.f; }
      w[i] = ww;
    }
    uint2 v[4];
#pragma unroll
    for (int i = 0; i < 4; i++){
      unsigned off = ((m[i] & 0xFFFFFFF0u) << 5) + colb;
      v[i] = *(const uint2*)(Xb + off);
    }
#pragma unroll
    for (int i = 0; i < 4; i++){
      f32x2 f01, f23;
      f01.x = asf(v[i].x << 16); f01.y = asf(v[i].x & 0xffff0000u);
      f23.x = asf(v[i].y << 16); f23.y = asf(v[i].y & 0xffff0000u);
      acc[0][0] += (f32x2){w[i].x, w[i].x} * f01;  acc[0][1] += (f32x2){w[i].x, w[i].x} * f23;
      acc[1][0] += (f32x2){w[i].y, w[i].y} * f01;  acc[1][1] += (f32x2){w[i].y, w[i].y} * f23;
      acc[2][0] += (f32x2){w[i].z, w[i].z} * f01;  acc[2][1] += (f32x2){w[i].z, w[i].z} * f23;
      acc[3][0] += (f32x2){w[i].w, w[i].w} * f01;  acc[3][1] += (f32x2){w[i].w, w[i].w} * f23;
    }
  }

#pragma unroll
  for (int b = 0; b < NBASES; b++){
    ushort4 o;
    o.x = f2bf(acc[b][0].x); o.y = f2bf(acc[b][0].y);
    o.z = f2bf(acc[b][1].x); o.w = f2bf(acc[b][1].y);
    *(ushort4*)(z + (size_t)d * KBASE + b * 256 + lane * 4) = o;
  }
}

// ---- MFMA GEMM: Y[M,256] = [z | ext] @ Wt^T + bias  (tile 64m x 256n, K=1280)
// mode 1: outh = relu(v) bf16 ; mode 2: outf = v fp32
// LDS k-slot XOR swizzle: granule (row, kc) lives at slot (kc + (row>>1))&3
__global__ __launch_bounds__(256) void gemm4(
    const unsigned short* __restrict__ A0,   // z [M,KBASE]
    const unsigned short* __restrict__ A1,   // ext [M,256]
    const unsigned short* __restrict__ Wt,   // [256,KW]
    const float* __restrict__ bias,
    unsigned short* __restrict__ outh,
    float* __restrict__ outf,
    int mode)
{
  __shared__ __attribute__((aligned(16))) short As[64 * 32];    // 4 KB
  __shared__ __attribute__((aligned(16))) short Bs[256 * 32];   // 16 KB
  int tid  = threadIdx.x;
  int m0   = blockIdx.x * 64;
  int lane = tid & 63;
  int wn   = tid >> 6;               // wave = n-slice 0..3
  int lq = lane >> 4, lr = lane & 15;

  f32x4 zero = {0.f, 0.f, 0.f, 0.f};
  f32x4 acc[4][4];
#pragma unroll
  for (int i = 0; i < 4; i++)
#pragma unroll
    for (int j = 0; j < 4; j++) acc[i][j] = zero;

  // A staging source params (row = tid>>2, kc = inverse swizzle)
  int arow = tid >> 2;
  int akc  = ((tid & 3) - (tid >> 3)) & 3;

  for (int k0 = 0; k0 < KW; k0 += 32){
    __syncthreads();
    {
      const unsigned short* ga;
      if (k0 < KBASE) ga = A0 + (size_t)(m0 + arow) * KBASE + k0 + akc * 8;
      else            ga = A1 + (size_t)(m0 + arow) * 256 + (k0 - KBASE) + akc * 8;
      gll16(ga, As + tid * 8);
    }
#pragma unroll
    for (int i = 0; i < 4; i++){
      int gb  = tid + i * 256;             // 0..1023 B granules
      int row = gb >> 2;
      int kc  = ((gb & 3) - (gb >> 3)) & 3;
      gll16(Wt + (size_t)row * KW + k0 + kc * 8, Bs + gb * 8);
    }
    __syncthreads();

    bf16x8 af[4], bfr[4];
#pragma unroll
    for (int i = 0; i < 4; i++){
      int row = i * 16 + lr;
      af[i] = *(const bf16x8*)(As + row * 32 + (((lq + (row >> 1)) & 3) * 8));
    }
#pragma unroll
    for (int j = 0; j < 4; j++){
      int row = wn * 64 + j * 16 + lr;
      bfr[j] = *(const bf16x8*)(Bs + row * 32 + (((lq + (row >> 1)) & 3) * 8));
    }
#pragma unroll
    for (int i = 0; i < 4; i++)
#pragma unroll
      for (int j = 0; j < 4; j++)
        acc[i][j] = __builtin_amdgcn_mfma_f32_16x16x32_bf16(af[i], bfr[j], acc[i][j], 0, 0, 0);
  }

  // C/D mapping: col=lane&15, row=(lane>>4)*4+reg  [m89/m91]
#pragma unroll
  for (int i = 0; i < 4; i++)
#pragma unroll
    for (int j = 0; j < 4; j++)
#pragma unroll
      for (int r = 0; r < 4; r++){
        int gm = m0 + i * 16 + lq * 4 + r;
        int gn = wn * 64 + j * 16 + lr;
        float v = acc[i][j][r] + bias[gn];
        size_t idx = (size_t)gm * 256 + gn;
        if (mode == 1) outh[idx] = f2bf(fmaxf(v, 0.f));
        else           outf[idx] = v;
      }
}

// ---------------------------------------------------------------------------
extern "C" void kernel_launch(void* const* d_in, const int* in_sizes, int n_in,
                              void* d_out, int out_size, void* d_ws, size_t ws_size,
                              hipStream_t stream)
{
  const float* x      = (const float*)d_in[0];
  const int*   ec     = (const int*)d_in[3];
  const int*   rel    = (const int*)d_in[4];
  const float* basis0 = (const float*)d_in[5];
  const float* comp0  = (const float*)d_in[6];
  const float* root0  = (const float*)d_in[7];
  const float* bias0  = (const float*)d_in[8];
  const float* basis1 = (const float*)d_in[9];
  const float* comp1  = (const float*)d_in[10];
  const float* root1  = (const float*)d_in[11];
  const float* bias1  = (const float*)d_in[12];

  char* p = (char*)d_ws;
  unsigned short* z   = (unsigned short*)p; p += (size_t)NNODES * KBASE * 2;  // 67.1 MB
  unsigned short* Xh  = (unsigned short*)p; p += (size_t)NNODES * DIM * 2;    // 16.8
  unsigned short* h   = (unsigned short*)p; p += (size_t)NNODES * DIM * 2;    // 16.8
  unsigned short* Wt0 = (unsigned short*)p; p += (size_t)256 * KW * 2;        // 0.66
  unsigned short* Wt1 = (unsigned short*)p; p += (size_t)256 * KW * 2;        // 0.66
  unsigned int* meta  = (unsigned int*)p;   p += (size_t)NEDGE * 4;           // 2.1
  int* cnt_rd  = (int*)p;   p += (size_t)NREL * NNODES * 4;                   // 1.3
  int* cursor  = (int*)p;   p += (size_t)NNODES * 4;
  int* offs    = (int*)p;   p += (size_t)(NNODES + 1) * 4;
  int* blksum  = (int*)p;   p += 1024;

  // zero cnt_rd + cursor (contiguous)
  hipMemsetAsync(cnt_rd, 0, ((size_t)NREL * NNODES + (size_t)NNODES) * 4, stream);

  // ---- fused prep: hist | conv | build Wt0 | build Wt1 ----
  mega_prep<<<HB + CB + 2 * WB, 256, 0, stream>>>(
      ec, rel, cnt_rd, x, Xh, basis0, root0, Wt0, basis1, root1, Wt1);

  scan1<<<NNODES / 1024, 1024, 0, stream>>>(cnt_rd, offs, blksum);
  scan2<<<1, 64, 0, stream>>>(blksum);
  scan3<<<NNODES / 1024, 1024, 0, stream>>>(offs, blksum);
  scatter_kernel<<<NEDGE / 256, 256, 0, stream>>>(ec, rel, offs, cursor, meta);

  // ---- layer 0 ----
  agg8<<<NNODES / 4, 256, 0, stream>>>(Xh, offs, meta, comp0, cnt_rd, z);
  gemm4<<<NNODES / 64, 256, 0, stream>>>(z, Xh, Wt0, bias0, h, nullptr, 1);

  // ---- layer 1 ----
  agg8<<<NNODES / 4, 256, 0, stream>>>(h, offs, meta, comp1, cnt_rd, z);
  gemm4<<<NNODES / 64, 256, 0, stream>>>(z, h, Wt1, bias1, nullptr, (float*)d_out, 2);
}